// Round 13
// baseline (985.126 us; speedup 1.0000x reference)
//
#include <hip/hip_runtime.h>
#include <math.h>

// DyHeadBlock forward. B=2, C=256, levels 64x64 / 32x32 / 16x16.
// Round 10: split-K=4 GEMM (64x64 per wave, atomicAdd epilogue) to fix the
// occupancy/latency wall; separate GN-stats pass; zero-init of GEMM outputs.

#define NB 2
#define NC 256

typedef __attribute__((ext_vector_type(8))) short bf16x8;
typedef __attribute__((ext_vector_type(4))) float f32x4;

static __device__ __forceinline__ float hsig_(float x){
  return fminf(fmaxf(x + 3.f, 0.f), 6.f) * (1.f/6.f);
}

static __device__ __forceinline__ unsigned short bf16r(float f){
  unsigned int u = __float_as_uint(f);
  unsigned int r = (u + 0x7FFFu + ((u >> 16) & 1u)) >> 16;   // RTNE
  return (unsigned short)r;
}

static __device__ __forceinline__ float bf2f(unsigned short u){
  return __uint_as_float(((unsigned int)u) << 16);
}

static __device__ __forceinline__ float blk_reduce(float v, float* buf){
  int t = threadIdx.x;
  buf[t] = v; __syncthreads();
  for(int s=128; s>0; s>>=1){
    if (t < s) buf[t] += buf[t+s];
    __syncthreads();
  }
  float r = buf[0];
  __syncthreads();
  return r;
}

// ---------------- zero region ----------------
__global__ __launch_bounds__(256) void zero_kernel(float* __restrict__ p, int n){
  int i = blockIdx.x*256 + threadIdx.x;
  if (i < n) p[i] = 0.f;
}

// ---------------- x transpose: x[b][ci][hw] f32 -> xt[b][hw][ci] bf16 ----------------
__global__ __launch_bounds__(256) void xpose_kernel(
    const float* __restrict__ x, unsigned short* __restrict__ xt, int N){
  __shared__ float tile[32][65];
  int t = threadIdx.x;
  int nb = N >> 6;
  int hw0 = (blockIdx.x % nb) * 64;
  int cg8 = (blockIdx.x / nb) & 7;
  int b   = blockIdx.x / (nb*8);
  int ci0 = cg8 * 32;
  const float* xb = x + ((size_t)(b*NC + ci0))*N;
  #pragma unroll
  for (int it = 0; it < 8; ++it){
    int idx = it*256 + t;
    int ci = idx >> 6, hwl = idx & 63;
    tile[ci][hwl] = xb[(size_t)ci*N + hw0 + hwl];
  }
  __syncthreads();
  int hwl = t >> 2, cg = t & 3;
  unsigned int ou[4];
  #pragma unroll
  for (int p = 0; p < 4; ++p){
    unsigned int lo = bf16r(tile[cg*8 + 2*p][hwl]);
    unsigned int hi = bf16r(tile[cg*8 + 2*p + 1][hwl]);
    ou[p] = lo | (hi << 16);
  }
  *(uint4*)(xt + ((size_t)b*N + hw0 + hwl)*256 + ci0 + cg*8) =
      make_uint4(ou[0], ou[1], ou[2], ou[3]);
}

// ---------------- conv_off, tiled ----------------
__global__ __launch_bounds__(256) void conv_off_tiled(
    const float* __restrict__ x, const float* __restrict__ w,
    float* __restrict__ partial, int H, int W, int tilesx){
  __shared__ float hl[18][20];
  __shared__ float wl[32][9][28];
  int b = blockIdx.z, chunk = blockIdx.y;
  int ty0 = (blockIdx.x / tilesx) * 16, tx0 = (blockIdx.x % tilesx) * 16;
  int t = threadIdx.x;
  int ci0 = chunk * 32;
  int N = H * W;
  for (int s = t; s < 27*32*9; s += 256){
    int c = s / 288, rem = s % 288, ci = rem / 9, k = rem % 9;
    wl[ci][k][c] = w[((size_t)(c*NC + ci0 + ci))*9 + k];
  }
  float acc[27];
  #pragma unroll
  for (int c = 0; c < 27; ++c) acc[c] = 0.f;
  int ty = t >> 4, tx = t & 15;
  for (int ci = 0; ci < 32; ++ci){
    const float* xc = x + ((size_t)(b*NC + ci0 + ci))*N;
    __syncthreads();
    for (int s = t; s < 324; s += 256){
      int hy = s / 18, hx = s % 18;
      int gy = ty0 + hy - 1, gx = tx0 + hx - 1;
      hl[hy][hx] = (gy >= 0 && gy < H && gx >= 0 && gx < W) ? xc[gy*W + gx] : 0.f;
    }
    __syncthreads();
    float xv[9];
    #pragma unroll
    for (int ky = 0; ky < 3; ++ky)
      #pragma unroll
      for (int kx = 0; kx < 3; ++kx)
        xv[ky*3+kx] = hl[ty+ky][tx+kx];
    #pragma unroll
    for (int k = 0; k < 9; ++k){
      float xk = xv[k];
      #pragma unroll
      for (int c4 = 0; c4 < 6; ++c4){
        float4 wv = *(float4*)&wl[ci][k][c4*4];
        acc[c4*4+0] = fmaf(wv.x, xk, acc[c4*4+0]);
        acc[c4*4+1] = fmaf(wv.y, xk, acc[c4*4+1]);
        acc[c4*4+2] = fmaf(wv.z, xk, acc[c4*4+2]);
        acc[c4*4+3] = fmaf(wv.w, xk, acc[c4*4+3]);
      }
      acc[24] = fmaf(wl[ci][k][24], xk, acc[24]);
      acc[25] = fmaf(wl[ci][k][25], xk, acc[25]);
      acc[26] = fmaf(wl[ci][k][26], xk, acc[26]);
    }
  }
  int hw = (ty0 + ty)*W + (tx0 + tx);
  float* pp = partial + ((size_t)(chunk*NB + b)*27)*N + hw;
  #pragma unroll
  for (int c = 0; c < 27; ++c) pp[(size_t)c*N] = acc[c];
}

__global__ __launch_bounds__(256) void conv_reduce(
    const float* __restrict__ partial, const float* __restrict__ bias,
    float* __restrict__ off, float* __restrict__ mask, int N){
  int idx = blockIdx.x*256 + threadIdx.x;
  int total = NB*27*N;
  if (idx >= total) return;
  int hw = idx % N;
  int c  = (idx / N) % 27;
  int b  = idx / (27*N);
  float s = bias[c];
  #pragma unroll
  for (int p = 0; p < 8; ++p)
    s += partial[((size_t)(p*NB + b)*27 + c)*N + hw];
  if (c < 18) off[((size_t)b*18 + c)*N + hw] = s;
  else        mask[((size_t)b*9 + (c-18))*N + hw] = 1.f/(1.f + expf(-s));
}

// ---------------- align-corners bilinear resize (+optional fused channel pool) ----------------
__global__ __launch_bounds__(256) void resize_pool_kernel(
    const float* __restrict__ in, float* __restrict__ out,
    float* __restrict__ pooled, int C, int H, int W, int Ho, int Wo){
  __shared__ float buf[256];
  int No = Ho*Wo;
  int idx = blockIdx.x*256 + threadIdx.x;
  int total = NB*C*No;
  float v = 0.f;
  int bc = 0;
  if (idx < total){
    int xo = idx % Wo;
    int yo = (idx / Wo) % Ho;
    bc = idx / No;
    float fy = (float)(H-1) / (float)(Ho-1);
    float fx = (float)(W-1) / (float)(Wo-1);
    float ys = yo * fy, xs = xo * fx;
    int y0 = (int)floorf(ys), x0i = (int)floorf(xs);
    int y1 = min(y0+1, H-1), x1 = min(x0i+1, W-1);
    float wy = ys - (float)y0, wx = xs - (float)x0i;
    const float* p = in + (size_t)bc*H*W;
    float v00 = p[y0*W+x0i], v01 = p[y0*W+x1];
    float v10 = p[y1*W+x0i], v11 = p[y1*W+x1];
    float r0 = v00*(1.f-wy) + v10*wy;
    float r1 = v01*(1.f-wy) + v11*wy;
    v = r0*(1.f-wx) + r1*wx;
    out[idx] = v;
  }
  if (pooled){
    float s = blk_reduce(v, buf);
    if (threadIdx.x == 0) atomicAdd(&pooled[bc], s);
  }
}

// ---------------- deformable sampling from xt -> cols[b][kp][hw][ci] bf16 ----------------
__global__ __launch_bounds__(256) void sample_t2_kernel(
    const unsigned short* __restrict__ xt, const float* __restrict__ off,
    const float* __restrict__ mask, unsigned short* __restrict__ cols,
    int Hi, int Wi, int Ho, int Wo, int stride){
  int N = Ho*Wo;
  int t = threadIdx.x;
  int c8 = t & 31, hw_l = t >> 5;
  int nb = N >> 3;
  int b  = blockIdx.x / nb;
  int hw = (blockIdx.x % nb)*8 + hw_l;
  int yo = hw / Wo, xo = hw % Wo;
  int HiWi = Hi*Wi;
  const unsigned short* xb = xt + (size_t)b*HiWi*256 + c8*8;
  const float* ob = off + (size_t)b*18*N;
  const float* mb = mask + (size_t)b*9*N;
  unsigned short* cb = cols + (size_t)b*9*N*256;
  float Hm1 = (float)(Hi-1), Wm1 = (float)(Wi-1);
  #pragma unroll
  for (int kp = 0; kp < 9; ++kp){
    int ky = kp/3, kx = kp%3;
    float py = (float)(yo*stride - 1 + ky) + ob[(size_t)(2*kp)*N + hw];
    float px = (float)(xo*stride - 1 + kx) + ob[(size_t)(2*kp+1)*N + hw];
    float m  = mb[(size_t)kp*N + hw];
    float y0f = floorf(py), x0f = floorf(px);
    float wy = py - y0f, wx = px - x0f;
    bool vy0 = (y0f >= 0.f)     && (y0f <= Hm1);
    bool vy1 = (y0f+1.f >= 0.f) && (y0f+1.f <= Hm1);
    bool vx0 = (x0f >= 0.f)     && (x0f <= Wm1);
    bool vx1 = (x0f+1.f >= 0.f) && (x0f+1.f <= Wm1);
    int y0i = min(max((int)y0f, 0), Hi-1);
    int y1i = min(max((int)y0f + 1, 0), Hi-1);
    int x0i = min(max((int)x0f, 0), Wi-1);
    int x1i = min(max((int)x0f + 1, 0), Wi-1);
    float w00 = (1.f-wy)*(1.f-wx) * (vy0 && vx0 ? 1.f : 0.f);
    float w01 = (1.f-wy)*wx       * (vy0 && vx1 ? 1.f : 0.f);
    float w10 = wy*(1.f-wx)       * (vy1 && vx0 ? 1.f : 0.f);
    float w11 = wy*wx             * (vy1 && vx1 ? 1.f : 0.f);
    const bf16x8 c00 = *(const bf16x8*)(xb + (size_t)(y0i*Wi + x0i)*256);
    const bf16x8 c01 = *(const bf16x8*)(xb + (size_t)(y0i*Wi + x1i)*256);
    const bf16x8 c10 = *(const bf16x8*)(xb + (size_t)(y1i*Wi + x0i)*256);
    const bf16x8 c11 = *(const bf16x8*)(xb + (size_t)(y1i*Wi + x1i)*256);
    unsigned int ou[4];
    #pragma unroll
    for (int p = 0; p < 4; ++p){
      float v0 = (w00*bf2f((unsigned short)c00[2*p])   + w01*bf2f((unsigned short)c01[2*p]) +
                  w10*bf2f((unsigned short)c10[2*p])   + w11*bf2f((unsigned short)c11[2*p])) * m;
      float v1 = (w00*bf2f((unsigned short)c00[2*p+1]) + w01*bf2f((unsigned short)c01[2*p+1]) +
                  w10*bf2f((unsigned short)c10[2*p+1]) + w11*bf2f((unsigned short)c11[2*p+1])) * m;
      ou[p] = (unsigned int)bf16r(v0) | ((unsigned int)bf16r(v1) << 16);
    }
    *(uint4*)(cb + ((size_t)kp*N + hw)*256 + c8*8) =
        make_uint4(ou[0], ou[1], ou[2], ou[3]);
  }
}

// ---------------- weight re-tile: At[chunk][co][8] bf16, chunk=kp*32+c8, m=kp*256+c8*8+e ----------------
__global__ __launch_bounds__(256) void wtrans_t_kernel(
    const float* __restrict__ w, unsigned short* __restrict__ At){
  int j = blockIdx.x*256 + threadIdx.x;
  if (j >= 2304*256) return;
  int e = j & 7, co = (j >> 3) & 255, chunk = j >> 11;
  int kp = chunk >> 5, ci = (chunk & 31)*8 + e;
  At[j] = bf16r(w[((size_t)(co*NC + ci))*9 + kp]);
}

// ---------------- MFMA GEMM, split-K=4, 64x64 per wave, atomicAdd epilogue ----------------
// grid: (N/64, 4 ksplit, NB), block 256 = 4 waves; wave wv -> co0 = wv*64.
// K chunks [ks*72, ks*72+72). C must be zero-initialized.
__global__ __launch_bounds__(256) void gemm_t3_kernel(
    const unsigned short* __restrict__ At,
    const unsigned short* __restrict__ cols,
    float* __restrict__ C, int N){
  int b = blockIdx.z;
  int ks = blockIdx.y;
  int hw0 = blockIdx.x * 64;
  int tid = threadIdx.x;
  int wv = tid >> 6, l = tid & 63;
  int co0 = wv * 64;
  int lr = l & 15, lg = l >> 4;
  const unsigned short* Bb = cols + (size_t)b*9*N*256;
  f32x4 acc[4][4];
  #pragma unroll
  for (int mi = 0; mi < 4; ++mi)
    #pragma unroll
    for (int ni = 0; ni < 4; ++ni)
      acc[mi][ni] = (f32x4){0.f, 0.f, 0.f, 0.f};
  int base = ks * 72;
  for (int kc = 0; kc < 72; kc += 4){
    int cidx = base + kc + lg;
    bf16x8 a[4], bv[4];
    #pragma unroll
    for (int mi = 0; mi < 4; ++mi)
      a[mi] = *(const bf16x8*)(At + ((size_t)cidx*256 + co0 + mi*16 + lr)*8);
    #pragma unroll
    for (int ni = 0; ni < 4; ++ni)
      bv[ni] = *(const bf16x8*)(Bb + ((size_t)(cidx >> 5)*N + hw0 + ni*16 + lr)*256 + (cidx & 31)*8);
    #pragma unroll
    for (int mi = 0; mi < 4; ++mi)
      #pragma unroll
      for (int ni = 0; ni < 4; ++ni)
        acc[mi][ni] = __builtin_amdgcn_mfma_f32_16x16x32_bf16(a[mi], bv[ni], acc[mi][ni], 0, 0, 0);
  }
  #pragma unroll
  for (int mi = 0; mi < 4; ++mi)
    #pragma unroll
    for (int ni = 0; ni < 4; ++ni)
      #pragma unroll
      for (int r = 0; r < 4; ++r){
        int row = co0 + mi*16 + lg*4 + r;
        int col = hw0 + ni*16 + lr;
        atomicAdd(&C[((size_t)b*NC + row)*N + col], acc[mi][ni][r]);
      }
}

// ---------------- GN stats (full grid): sum/sumsq per group via block-reduce + atomics ----------------
__global__ __launch_bounds__(256) void stats_kernel(
    const float* __restrict__ f, float* __restrict__ stats, int N){
  __shared__ float b1[256];
  __shared__ float b2[256];
  int idx = blockIdx.x*256 + threadIdx.x;
  int c = (idx / N) & (NC-1);
  int b = idx / (NC*N);
  float v = f[idx];
  float s  = blk_reduce(v, b1);
  float ss = blk_reduce(v*v, b2);
  if (threadIdx.x == 0){
    int g = b*16 + (c >> 4);
    atomicAdd(&stats[g*2],     s);
    atomicAdd(&stats[g*2 + 1], ss);
  }
}

// ---------------- GN apply + fused channel pool ----------------
__global__ __launch_bounds__(256) void gn_apply_pool(
    float* __restrict__ f, const float* __restrict__ gamma,
    const float* __restrict__ beta, const float* __restrict__ stats,
    float* __restrict__ pooled, int N, float inv_cnt){
  __shared__ float buf[256];
  int idx = blockIdx.x*256 + threadIdx.x;
  int c = (idx / N) & (NC-1);
  int b = idx / (NC*N);
  int g = b*16 + (c >> 4);
  float s_  = stats[g*2];
  float ss_ = stats[g*2 + 1];
  float mu  = s_ * inv_cnt;
  float var = ss_ * inv_cnt - mu*mu;
  float rstd = rsqrtf(var + 1e-5f);
  float v = (f[idx] - mu)*rstd*gamma[c] + beta[c];
  f[idx] = v;
  if (pooled){
    float bs = blk_reduce(v, buf);
    if (threadIdx.x == 0) atomicAdd(&pooled[b*NC + c], bs);
  }
}

// ---------------- scale attention scalar ----------------
__global__ __launch_bounds__(256) void attn_kernel(
    const float* __restrict__ pooled, const float* __restrict__ wsc,
    const float* __restrict__ bsc, float* __restrict__ scal, float inv_N){
  __shared__ float buf[256];
  int b = blockIdx.x;
  float v = pooled[b*NC + threadIdx.x] * inv_N * wsc[threadIdx.x];
  float t = blk_reduce(v, buf);
  if (threadIdx.x == 0){
    float z = fmaxf(t + bsc[0], 0.f);
    scal[b] = hsig_(z);
  }
}

// ---------------- weighted combine + fused plsum pool ----------------
__global__ __launch_bounds__(256) void combine_pool_kernel(
    const float* __restrict__ fm, const float* __restrict__ fl,
    const float* __restrict__ fh, const float* __restrict__ scal,
    float* __restrict__ outp, float* __restrict__ plsum,
    int N, float inv_n){
  __shared__ float buf[256];
  int idx = blockIdx.x*256 + threadIdx.x;
  int b = idx / (NC*N);
  int c = (idx / N) & (NC-1);
  float v = fm[idx] * scal[b];
  if (fl) v = fmaf(fl[idx], scal[2+b], v);
  if (fh) v = fmaf(fh[idx], scal[4+b], v);
  v *= inv_n;
  outp[idx] = v;
  float bs = blk_reduce(v, buf);
  if (threadIdx.x == 0) atomicAdd(&plsum[b*NC + c], bs);
}

// ---------------- DyReLU MLP ----------------
__global__ __launch_bounds__(256) void dyrelu_mlp_kernel(
    const float* __restrict__ plsum,
    const float* __restrict__ w1, const float* __restrict__ b1,
    const float* __restrict__ w2, const float* __restrict__ b2,
    float* __restrict__ coef, float inv_N){
  __shared__ float pld[256];
  __shared__ float h[64];
  int b = blockIdx.x, t = threadIdx.x;
  pld[t] = plsum[b*NC + t] * inv_N;
  __syncthreads();
  if (t < 64){
    float a = b1[t];
    for(int c=0; c<256; ++c) a = fmaf(w1[t*256 + c], pld[c], a);
    h[t] = fmaxf(a, 0.f);
  }
  __syncthreads();
  for(int q=0; q<4; ++q){
    int o = q*256 + t;
    float a = b2[o];
    #pragma unroll 8
    for(int k=0; k<64; ++k) a = fmaf(w2[o*64 + k], h[k], a);
    coef[b*1024 + o] = hsig_(a) - 0.5f;
  }
}

// ---------------- DyReLU apply ----------------
__global__ __launch_bounds__(256) void dyrelu_apply_kernel(
    const float* __restrict__ sf, const float* __restrict__ coef,
    float* __restrict__ out, int N){
  int idx = blockIdx.x*256 + threadIdx.x;
  int c = (idx / N) & (NC-1);
  int b = idx / (NC*N);
  const float* cf = coef + b*1024;
  float a1 = fmaf(cf[c], 2.f, 1.f);
  float bb1 = cf[256 + c];
  float a2 = cf[512 + c]*2.f;
  float bb2 = cf[768 + c];
  float v = sf[idx];
  out[idx] = fmaxf(fmaf(v, a1, bb1), fmaf(v, a2, bb2));
}

extern "C" void kernel_launch(void* const* d_in, const int* in_sizes, int n_in,
                              void* d_out, int out_size, void* d_ws, size_t ws_size,
                              hipStream_t stream){
  const float* x0      = (const float*)d_in[0];
  const float* x1      = (const float*)d_in[1];
  const float* x2      = (const float*)d_in[2];
  const float* w_off   = (const float*)d_in[3];
  const float* b_off   = (const float*)d_in[4];
  const float* w_mid   = (const float*)d_in[5];
  const float* g_mid   = (const float*)d_in[6];
  const float* bt_mid  = (const float*)d_in[7];
  const float* w_low   = (const float*)d_in[8];
  const float* g_low   = (const float*)d_in[9];
  const float* bt_low  = (const float*)d_in[10];
  const float* w_high  = (const float*)d_in[11];
  const float* g_high  = (const float*)d_in[12];
  const float* bt_high = (const float*)d_in[13];
  const float* w_scale = (const float*)d_in[14];
  const float* b_scale = (const float*)d_in[15];
  const float* w1      = (const float*)d_in[16];
  const float* b1      = (const float*)d_in[17];
  const float* w2      = (const float*)d_in[18];
  const float* b2      = (const float*)d_in[19];
  float* out = (float*)d_out;

  char* wp_ = (char*)d_ws;
  auto alloc = [&](size_t bytes) -> char* {
    char* r = wp_;
    wp_ += (bytes + 255) & ~(size_t)255;
    return r;
  };
  float* off0  = (float*)alloc((size_t)NB*18*4096*4);
  float* off1  = (float*)alloc((size_t)NB*18*1024*4);
  float* off2  = (float*)alloc((size_t)NB*18*256*4);
  float* mask0 = (float*)alloc((size_t)NB*9*4096*4);
  float* mask1 = (float*)alloc((size_t)NB*9*1024*4);
  float* mask2 = (float*)alloc((size_t)NB*9*256*4);
  float* offr  = (float*)alloc((size_t)NB*18*1024*4);
  float* maskr = (float*)alloc((size_t)NB*9*1024*4);
  float* partial = (float*)alloc((size_t)8*NB*27*4096*4);
  unsigned short* Atm = (unsigned short*)alloc((size_t)2304*256*2);
  unsigned short* Atl = (unsigned short*)alloc((size_t)2304*256*2);
  unsigned short* Ath = (unsigned short*)alloc((size_t)2304*256*2);
  unsigned short* xt0 = (unsigned short*)alloc((size_t)NB*4096*256*2);
  unsigned short* xt1 = (unsigned short*)alloc((size_t)NB*1024*256*2);
  unsigned short* xt2 = (unsigned short*)alloc((size_t)NB*256*256*2);
  unsigned short* colsT = (unsigned short*)alloc((size_t)NB*9*4096*256*2);
  float* fmid  = (float*)alloc((size_t)NB*NC*4096*4);
  float* flow  = (float*)alloc((size_t)NB*NC*4096*4);
  float* fhis  = (float*)alloc((size_t)NB*NC*1024*4);
  float* fhi   = (float*)alloc((size_t)NB*NC*4096*4);
  float* sumf  = (float*)alloc((size_t)NB*NC*4096*4);
  float* statsm = (float*)alloc((size_t)(64*3 + 512*4)*4);
  float* statsl = statsm + 64;
  float* statsh = statsm + 128;
  float* plmid  = statsm + 192;
  float* pllow  = plmid + 512;
  float* plhi   = plmid + 1024;
  float* plsum  = plmid + 1536;
  const int ZN = 64*3 + 512*4;
  float* scal  = (float*)alloc(8*4);
  float* coef  = (float*)alloc((size_t)NB*1024*4);
  (void)ws_size; (void)in_sizes; (void)n_in; (void)out_size;

  wtrans_t_kernel<<<2304, 256, 0, stream>>>(w_mid, Atm);
  wtrans_t_kernel<<<2304, 256, 0, stream>>>(w_low, Atl);
  wtrans_t_kernel<<<2304, 256, 0, stream>>>(w_high, Ath);
  xpose_kernel<<<NB*8*(4096/64), 256, 0, stream>>>(x0, xt0, 4096);
  xpose_kernel<<<NB*8*(1024/64), 256, 0, stream>>>(x1, xt1, 1024);
  xpose_kernel<<<NB*8*(256/64),  256, 0, stream>>>(x2, xt2, 256);

  const int   sizes[3] = {64, 32, 16};
  const float* xs[3]   = {x0, x1, x2};
  const unsigned short* xts[3] = {xt0, xt1, xt2};
  float* OFF[3]  = {off0, off1, off2};
  float* MASK[3] = {mask0, mask1, mask2};
  const size_t outoff[3] = {0, (size_t)NB*NC*4096, (size_t)NB*NC*4096 + (size_t)NB*NC*1024};

  for(int l=0; l<3; ++l){
    int H = sizes[l], W = H, N = H*W;
    int totBCN = NB*NC*N;
    int tilesx = H/16;
    float invN = 1.f/(float)N;
    float inv_cnt = 1.f/(float)(16*N);

    zero_kernel<<<(ZN+255)/256, 256, 0, stream>>>(statsm, ZN);

    conv_off_tiled<<<dim3(tilesx*tilesx, 8, NB), 256, 0, stream>>>(
        xs[l], w_off, partial, H, W, tilesx);
    conv_reduce<<<(NB*27*N+255)/256, 256, 0, stream>>>(
        partial, b_off, OFF[l], MASK[l], N);

    // ---- mid ----
    zero_kernel<<<totBCN/256, 256, 0, stream>>>(fmid, totBCN);
    sample_t2_kernel<<<NB*(N/8), 256, 0, stream>>>(
        xts[l], OFF[l], MASK[l], colsT, H, W, H, W, 1);
    gemm_t3_kernel<<<dim3(N/64, 4, NB), 256, 0, stream>>>(Atm, colsT, fmid, N);
    stats_kernel<<<totBCN/256, 256, 0, stream>>>(fmid, statsm, N);
    gn_apply_pool<<<totBCN/256, 256, 0, stream>>>(fmid, g_mid, bt_mid, statsm, plmid, N, inv_cnt);
    attn_kernel<<<NB, 256, 0, stream>>>(plmid, w_scale, b_scale, scal + 0, invN);

    int nf = 1;
    const float* flowp = nullptr;
    const float* fhip  = nullptr;

    // ---- low (stride-2 from previous, finer level) ----
    if (l > 0){
      int Hp = sizes[l-1];
      zero_kernel<<<totBCN/256, 256, 0, stream>>>(flow, totBCN);
      sample_t2_kernel<<<NB*(N/8), 256, 0, stream>>>(
          xts[l-1], OFF[l], MASK[l], colsT, Hp, Hp, H, W, 2);
      gemm_t3_kernel<<<dim3(N/64, 4, NB), 256, 0, stream>>>(Atl, colsT, flow, N);
      stats_kernel<<<totBCN/256, 256, 0, stream>>>(flow, statsl, N);
      gn_apply_pool<<<totBCN/256, 256, 0, stream>>>(flow, g_low, bt_low, statsl, pllow, N, inv_cnt);
      attn_kernel<<<NB, 256, 0, stream>>>(pllow, w_scale, b_scale, scal + 2, invN);
      nf++; flowp = flow;
    }

    // ---- high (next, coarser level) ----
    if (l < 2){
      int Ht = sizes[l+1], Nt = Ht*Ht;
      int totH = NB*NC*Nt;
      float inv_cnt_h = 1.f/(float)(16*Nt);
      resize_pool_kernel<<<(NB*18*Nt+255)/256, 256, 0, stream>>>(OFF[l], offr, nullptr, 18, H, W, Ht, Ht);
      resize_pool_kernel<<<(NB*9*Nt+255)/256, 256, 0, stream>>>(MASK[l], maskr, nullptr, 9, H, W, Ht, Ht);
      zero_kernel<<<totH/256, 256, 0, stream>>>(fhis, totH);
      sample_t2_kernel<<<NB*(Nt/8), 256, 0, stream>>>(
          xts[l+1], offr, maskr, colsT, Ht, Ht, Ht, Ht, 1);
      gemm_t3_kernel<<<dim3(Nt/64, 4, NB), 256, 0, stream>>>(Ath, colsT, fhis, Nt);
      stats_kernel<<<totH/256, 256, 0, stream>>>(fhis, statsh, Nt);
      gn_apply_pool<<<totH/256, 256, 0, stream>>>(fhis, g_high, bt_high, statsh, nullptr, Nt, inv_cnt_h);
      resize_pool_kernel<<<totBCN/256, 256, 0, stream>>>(fhis, fhi, plhi, NC, Ht, Ht, H, W);
      attn_kernel<<<NB, 256, 0, stream>>>(plhi, w_scale, b_scale, scal + 4, invN);
      nf++; fhip = fhi;
    }

    // ---- combine + DyReLU ----
    combine_pool_kernel<<<totBCN/256, 256, 0, stream>>>(
        fmid, flowp, fhip, scal, sumf, plsum, N, 1.f/(float)nf);
    dyrelu_mlp_kernel<<<NB, 256, 0, stream>>>(plsum, w1, b1, w2, b2, coef, invN);
    dyrelu_apply_kernel<<<totBCN/256, 256, 0, stream>>>(
        sumf, coef, out + outoff[l], N);
  }
}